// Round 9
// baseline (158.116 us; speedup 1.0000x reference)
//
#include <hip/hip_runtime.h>
#include <hip/hip_fp16.h>

// Separable 3D Gaussian blur (sigma=1, truncate=3 -> 7 taps), SAME zero padding.
// (N=2, D=160, H=160, W=160, C=4) float32 == float4 over C.
// Round 9 (from round-8 base):
//  - wb tile stored as fp16 (half4 packed in uint2): H-blur reads are b64,
//    wb LDS 11.6->5.8 KB; total LDS 19.5 KB -> 8 blocks/CU capacity.
//  - 2-slice-deep register prefetch (named A/B sets, loop unrolled x2, all
//    indices static) -> commit's ds_write no longer waits on fresh vmcnt.
//  - bijective XCD-chunked block swizzle (1600 = 8 x 200): spatial/D
//    neighbor tiles share an XCD L2 -> halo re-reads become L2 hits.
//  - launch_bounds(256,4): VGPR cap 128 (rings 56 + prefetch 32 + consts).
// Skeleton unchanged: stage coalesced -> raw LDS; 176 W-workers read 10xb128
// -> 4 fp16 wb outputs; 256 threads H-blur (8xb64) -> dual 7-deep D-rings;
// two lgkmcnt-only barriers per slice (no vmcnt drain).

#define THT 16             // tile height (H outputs)
#define TWT 32             // tile width  (W outputs)
#define CHUNK 10           // output D-slices per block
#define DIM 160
#define SLICE (DIM * DIM)  // float4 elements per (D) slice
#define RAWN (22 * 38)     // staged halo f4 per slice = 836
#define NBLK 1600          // 2 * 10 * 5 * 16

#define W0 0.004433048f
#define W1 0.054005582f
#define W2 0.242036229f
#define W3 0.399050300f

__device__ __forceinline__ float4 blur7(float4 a0, float4 a1, float4 a2, float4 a3,
                                        float4 a4, float4 a5, float4 a6) {
    float4 r;
    r.x = W0 * (a0.x + a6.x) + W1 * (a1.x + a5.x) + W2 * (a2.x + a4.x) + W3 * a3.x;
    r.y = W0 * (a0.y + a6.y) + W1 * (a1.y + a5.y) + W2 * (a2.y + a4.y) + W3 * a3.y;
    r.z = W0 * (a0.z + a6.z) + W1 * (a1.z + a5.z) + W2 * (a2.z + a4.z) + W3 * a3.z;
    r.w = W0 * (a0.w + a6.w) + W1 * (a1.w + a5.w) + W2 * (a2.w + a4.w) + W3 * a3.w;
    return r;
}

__device__ __forceinline__ uint2 pack_h4(float4 v) {
    __half2 lo = __floats2half2_rn(v.x, v.y);
    __half2 hi = __floats2half2_rn(v.z, v.w);
    uint2 r;
    r.x = *(unsigned int*)&lo;
    r.y = *(unsigned int*)&hi;
    return r;
}

__device__ __forceinline__ float4 unpack_h4(uint2 u) {
    __half2 lo = *(__half2*)&u.x;
    __half2 hi = *(__half2*)&u.y;
    float2 a = __half22float2(lo);
    float2 b = __half22float2(hi);
    return make_float4(a.x, a.y, b.x, b.y);
}

// Workgroup barrier with LDS visibility but NO vmcnt(0) drain.
__device__ __forceinline__ void lds_barrier() {
    asm volatile("s_waitcnt lgkmcnt(0)" ::: "memory");
    __builtin_amdgcn_s_barrier();
}

__global__ __launch_bounds__(256, 4)
void gauss3d_fused(const float4* __restrict__ in, float4* __restrict__ out) {
    // XCD-chunked bijective swizzle: 1600 blocks = 8 XCDs x 200.
    // Blocks with bid%8==x run on XCD x and get work ids [x*200, x*200+200):
    // 200 contiguous work ids = all 50 (tw,th) tiles x 4 D-chunks -> spatial
    // and D neighbors share an XCD L2.
    int work = (blockIdx.x & 7) * (NBLK / 8) + (blockIdx.x >> 3);
    const int tw    = work % (DIM / TWT);   work /= (DIM / TWT);   // 5
    const int th    = work % (DIM / THT);   work /= (DIM / THT);   // 10
    const int chunk = work % (DIM / CHUNK); work /= (DIM / CHUNK); // 16
    const int n     = work;                                        // 2

    const int h0 = th * THT;
    const int w0 = tw * TWT;
    const int d0 = chunk * CHUNK;

    __shared__ float4 raw[22][39];  // halo 22(H) x 38(W) f32, odd col pad
    __shared__ uint2  wb[22][33];   // W-blurred 22 x 32 fp16x4, odd col pad

    const int tid = threadIdx.x;
    const size_t nbase = (size_t)n * DIM * SLICE;
    const float4 z = make_float4(0.f, 0.f, 0.f, 0.f);

    // ---- stage constants: 836 halo f4 over 256 threads (<=4 slots) ----
    int  soff[4], rbidx[4];
    bool sok[4];
    #pragma unroll
    for (int s = 0; s < 4; ++s) {
        const int i = tid + 256 * s;
        const bool has = (i < RAWN);
        const int rr = has ? (i / 38) : 0, cc = has ? (i % 38) : 0;
        const int gh = h0 + rr - 3, gw = w0 + cc - 3;
        const bool ok = has && gh >= 0 && gh < DIM && gw >= 0 && gw < DIM;
        soff[s]  = ok ? (gh * DIM + gw) : 0;
        sok[s]   = ok;
        rbidx[s] = rr * 39 + cc;
    }
    const bool shas3 = (tid + 768 < RAWN);

    // ---- W-blur workers: 176 = 22 rows x 8 groups of 4 cols ----
    const bool isW = (tid < 176);
    const int wr  = tid >> 3;        // 0..21
    const int wc0 = (tid & 7) * 4;   // 0,4,...,28

    // ---- H-blur: 256 threads = 8 H-pairs x 32 cols ----
    const int hp = tid >> 5;         // 0..7 -> output rows 2hp, 2hp+1
    const int lw = tid & 31;         // 0..31

    // prefetch register sets (A = even slices, B = odd), 2 slices deep
    float4 pA0, pA1, pA2, pA3, pB0, pB1, pB2, pB3;
    float4 a0 = z, a1 = z, a2 = z, a3 = z, a4 = z, a5 = z, a6 = z;
    float4 b0 = z, b1 = z, b2 = z, b3 = z, b4 = z, b5 = z, b6 = z;

#define PREF(P0, P1, P2, P3, DSL)                                            \
    do {                                                                     \
        const int _d = (DSL);                                                \
        const bool _ir = (_d >= 0) && (_d < DIM);                            \
        const float4* _s = in + nbase + (size_t)(_ir ? _d : 0) * SLICE;      \
        P0 = (_ir && sok[0]) ? _s[soff[0]] : z;                              \
        P1 = (_ir && sok[1]) ? _s[soff[1]] : z;                              \
        P2 = (_ir && sok[2]) ? _s[soff[2]] : z;                              \
        P3 = (_ir && sok[3]) ? _s[soff[3]] : z;                              \
    } while (0)

#define COMMIT(P0, P1, P2, P3)                                               \
    do {                                                                     \
        float4* rb = &raw[0][0];                                             \
        rb[rbidx[0]] = P0;                                                   \
        rb[rbidx[1]] = P1;                                                   \
        rb[rbidx[2]] = P2;                                                   \
        if (shas3) rb[rbidx[3]] = P3;                                        \
    } while (0)

#define WPHASE()                                                             \
    do {                                                                     \
        if (isW) {                                                           \
            float4 rv0 = raw[wr][wc0 + 0];                                   \
            float4 rv1 = raw[wr][wc0 + 1];                                   \
            float4 rv2 = raw[wr][wc0 + 2];                                   \
            float4 rv3 = raw[wr][wc0 + 3];                                   \
            float4 rv4 = raw[wr][wc0 + 4];                                   \
            float4 rv5 = raw[wr][wc0 + 5];                                   \
            float4 rv6 = raw[wr][wc0 + 6];                                   \
            float4 rv7 = raw[wr][wc0 + 7];                                   \
            float4 rv8 = raw[wr][wc0 + 8];                                   \
            float4 rv9 = raw[wr][wc0 + 9];                                   \
            wb[wr][wc0 + 0] = pack_h4(blur7(rv0, rv1, rv2, rv3, rv4, rv5, rv6)); \
            wb[wr][wc0 + 1] = pack_h4(blur7(rv1, rv2, rv3, rv4, rv5, rv6, rv7)); \
            wb[wr][wc0 + 2] = pack_h4(blur7(rv2, rv3, rv4, rv5, rv6, rv7, rv8)); \
            wb[wr][wc0 + 3] = pack_h4(blur7(rv3, rv4, rv5, rv6, rv7, rv8, rv9)); \
        }                                                                    \
    } while (0)

#define HPHASE(DIN)                                                          \
    do {                                                                     \
        float4 c0 = unpack_h4(wb[2 * hp + 0][lw]);                           \
        float4 c1 = unpack_h4(wb[2 * hp + 1][lw]);                           \
        float4 c2 = unpack_h4(wb[2 * hp + 2][lw]);                           \
        float4 c3 = unpack_h4(wb[2 * hp + 3][lw]);                           \
        float4 c4 = unpack_h4(wb[2 * hp + 4][lw]);                           \
        float4 c5 = unpack_h4(wb[2 * hp + 5][lw]);                           \
        float4 c6 = unpack_h4(wb[2 * hp + 6][lw]);                           \
        float4 c7 = unpack_h4(wb[2 * hp + 7][lw]);                           \
        float4 va = blur7(c0, c1, c2, c3, c4, c5, c6);                       \
        float4 vb = blur7(c1, c2, c3, c4, c5, c6, c7);                       \
        a0 = a1; a1 = a2; a2 = a3; a3 = a4; a4 = a5; a5 = a6; a6 = va;       \
        b0 = b1; b1 = b2; b2 = b3; b3 = b4; b4 = b5; b5 = b6; b6 = vb;       \
        const int dout = (DIN) - 3;                                          \
        if (dout >= d0) {                                                    \
            float4 oa = blur7(a0, a1, a2, a3, a4, a5, a6);                   \
            float4 ob = blur7(b0, b1, b2, b3, b4, b5, b6);                   \
            const size_t base = nbase + (size_t)dout * SLICE;                \
            out[base + (size_t)(h0 + 2 * hp + 0) * DIM + (w0 + lw)] = oa;    \
            out[base + (size_t)(h0 + 2 * hp + 1) * DIM + (w0 + lw)] = ob;    \
        }                                                                    \
    } while (0)

    PREF(pA0, pA1, pA2, pA3, d0 - 3);
    PREF(pB0, pB1, pB2, pB3, d0 - 2);

    for (int it = 0; it < (CHUNK + 6) / 2; ++it) {   // 8 double-iterations
        const int de = d0 - 3 + 2 * it;              // even slice
        COMMIT(pA0, pA1, pA2, pA3);
        if (de + 2 <= d0 + CHUNK + 2) PREF(pA0, pA1, pA2, pA3, de + 2);
        lds_barrier();   // A: raw visible; prev H reads of wb drained
        WPHASE();
        lds_barrier();   // B: wb visible; raw reads drained
        HPHASE(de);

        const int dd = de + 1;                       // odd slice
        COMMIT(pB0, pB1, pB2, pB3);
        if (dd + 2 <= d0 + CHUNK + 2) PREF(pB0, pB1, pB2, pB3, dd + 2);
        lds_barrier();
        WPHASE();
        lds_barrier();
        HPHASE(dd);
    }
#undef PREF
#undef COMMIT
#undef WPHASE
#undef HPHASE
}

extern "C" void kernel_launch(void* const* d_in, const int* in_sizes, int n_in,
                              void* d_out, int out_size, void* d_ws, size_t ws_size,
                              hipStream_t stream) {
    const float4* in = (const float4*)d_in[0];
    float4* out = (float4*)d_out;
    gauss3d_fused<<<NBLK, 256, 0, stream>>>(in, out);
}

// Round 10
// 79.860 us; speedup vs baseline: 1.9799x; 1.9799x over previous
//
#include <hip/hip_runtime.h>

// Separable 3D Gaussian blur (sigma=1, truncate=3 -> 7 taps), SAME zero padding.
// (N=2, D=160, H=160, W=160, C=4) float32 == float4 over C.
// Round 10 = round 6 (best: 80.5us) + ONE change: bijective XCD-chunked
// blockIdx swizzle. 1000 blocks = 8 XCDs x 125 contiguous work ids; blocks
// with bid%8==x land on XCD x and process a contiguous plane of tiles ->
// in-plane halo re-reads become same-XCD L2 hits (working set ~3.3MB < 4MB).
// Everything else identical to round 6:
//  tile 16(H) x 32(W), CHUNK=16, dbuf raw (39.4KB LDS), f32 wb,
//  176 W-workers x (10 raw reads -> 4 wb outputs), H-pairs with dual 7-deep
//  D rings, register prefetch 1 slice ahead, 2 lgkmcnt-only barriers/slice,
//  launch_bounds(256,4) (VGPR cap 128 -- (256,6) spilled in R7, (256,8) in R3).

#define THT 16             // tile height (H outputs)
#define TWT 32             // tile width  (W outputs)
#define CHUNK 16           // output D-slices per block
#define DIM 160
#define SLICE (DIM * DIM)  // float4 elements per (D) slice
#define RAWN (22 * 38)     // staged halo f4 per slice = 836
#define NBLK 1000          // 2 * 10 * 5 * 10

#define W0 0.004433048f
#define W1 0.054005582f
#define W2 0.242036229f
#define W3 0.399050300f

__device__ __forceinline__ float4 blur7(float4 a0, float4 a1, float4 a2, float4 a3,
                                        float4 a4, float4 a5, float4 a6) {
    float4 r;
    r.x = W0 * (a0.x + a6.x) + W1 * (a1.x + a5.x) + W2 * (a2.x + a4.x) + W3 * a3.x;
    r.y = W0 * (a0.y + a6.y) + W1 * (a1.y + a5.y) + W2 * (a2.y + a4.y) + W3 * a3.y;
    r.z = W0 * (a0.z + a6.z) + W1 * (a1.z + a5.z) + W2 * (a2.z + a4.z) + W3 * a3.z;
    r.w = W0 * (a0.w + a6.w) + W1 * (a1.w + a5.w) + W2 * (a2.w + a4.w) + W3 * a3.w;
    return r;
}

// Workgroup barrier with LDS visibility but NO vmcnt(0) drain -> prefetched
// global loads stay in flight across it.
__device__ __forceinline__ void lds_barrier() {
    asm volatile("s_waitcnt lgkmcnt(0)" ::: "memory");
    __builtin_amdgcn_s_barrier();
}

__global__ __launch_bounds__(256, 4)
void gauss3d_fused(const float4* __restrict__ in, float4* __restrict__ out) {
    // XCD-chunked bijective swizzle: 1000 = 8 * 125 exactly.
    int work = (blockIdx.x & 7) * (NBLK / 8) + (blockIdx.x >> 3);
    // decode: tw innermost (W-adjacent tiles contiguous), then th, chunk, n.
    const int tw    = work % (DIM / TWT);   work /= (DIM / TWT);   // 5
    const int th    = work % (DIM / THT);   work /= (DIM / THT);   // 10
    const int chunk = work % (DIM / CHUNK); work /= (DIM / CHUNK); // 10
    const int n     = work;                                        // 2

    const int h0 = th * THT;
    const int w0 = tw * TWT;
    const int d0 = chunk * CHUNK;

    __shared__ float4 raw[2][22][39];  // halo 22(H) x 38(W), odd pad, dbuf
    __shared__ float4 wb[22][33];      // W-blurred 22 x 32, odd pad

    const int tid = threadIdx.x;
    const size_t nbase = (size_t)n * DIM * SLICE;
    const float4 z = make_float4(0.f, 0.f, 0.f, 0.f);

    // ---- stage constants: 836 halo f4 over 256 threads (<=4 slots) ----
    int  soff[4], rbidx[4];
    bool sok[4];
    #pragma unroll
    for (int s = 0; s < 4; ++s) {
        const int i = tid + 256 * s;
        const bool has = (i < RAWN);
        const int rr = has ? (i / 38) : 0, cc = has ? (i % 38) : 0;
        const int gh = h0 + rr - 3, gw = w0 + cc - 3;
        const bool ok = has && gh >= 0 && gh < DIM && gw >= 0 && gw < DIM;
        soff[s]  = ok ? (gh * DIM + gw) : 0;
        sok[s]   = ok;
        rbidx[s] = rr * 39 + cc;
    }
    const bool shas3 = (tid + 768 < RAWN);

    // ---- W-blur workers: 176 = 22 rows x 8 groups of 4 cols ----
    const bool isW = (tid < 176);
    const int wr  = tid >> 3;        // 0..21
    const int wc0 = (tid & 7) * 4;   // 0,4,...,28

    // ---- H-blur: 256 threads = 8 H-pairs x 32 cols ----
    const int hp = tid >> 5;         // 0..7 -> output rows 2hp, 2hp+1
    const int lw = tid & 31;         // 0..31

    float4 pf0, pf1, pf2, pf3;
    float4 a0 = z, a1 = z, a2 = z, a3 = z, a4 = z, a5 = z, a6 = z;  // ring row 2hp
    float4 b0 = z, b1 = z, b2 = z, b3 = z, b4 = z, b5 = z, b6 = z;  // ring row 2hp+1

#define PREFETCH(DSL)                                                        \
    do {                                                                     \
        const int _d = (DSL);                                                \
        const bool _inr = (_d >= 0) && (_d < DIM);                           \
        const float4* _s = in + nbase + (size_t)(_inr ? _d : 0) * SLICE;     \
        pf0 = (_inr && sok[0]) ? _s[soff[0]] : z;                            \
        pf1 = (_inr && sok[1]) ? _s[soff[1]] : z;                            \
        pf2 = (_inr && sok[2]) ? _s[soff[2]] : z;                            \
        pf3 = (_inr && sok[3]) ? _s[soff[3]] : z;                            \
    } while (0)

    PREFETCH(d0 - 3);
    int buf = 0;

    for (int din = d0 - 3; din <= d0 + CHUNK + 2; ++din) {
        // 1) commit prefetched slice into raw[buf]
        {
            float4* rb = &raw[buf][0][0];
            rb[rbidx[0]] = pf0;
            rb[rbidx[1]] = pf1;
            rb[rbidx[2]] = pf2;
            if (shas3) rb[rbidx[3]] = pf3;
        }

        // 2) issue next slice's loads; in flight across both barriers
        PREFETCH(din + 1);

        lds_barrier();  // A: raw[buf] visible; prev H-blur reads of wb drained

        // 3) W-blur: 176 workers, 10 raw reads -> 4 wb outputs each
        if (isW) {
            float4 rv0 = raw[buf][wr][wc0 + 0];
            float4 rv1 = raw[buf][wr][wc0 + 1];
            float4 rv2 = raw[buf][wr][wc0 + 2];
            float4 rv3 = raw[buf][wr][wc0 + 3];
            float4 rv4 = raw[buf][wr][wc0 + 4];
            float4 rv5 = raw[buf][wr][wc0 + 5];
            float4 rv6 = raw[buf][wr][wc0 + 6];
            float4 rv7 = raw[buf][wr][wc0 + 7];
            float4 rv8 = raw[buf][wr][wc0 + 8];
            float4 rv9 = raw[buf][wr][wc0 + 9];
            wb[wr][wc0 + 0] = blur7(rv0, rv1, rv2, rv3, rv4, rv5, rv6);
            wb[wr][wc0 + 1] = blur7(rv1, rv2, rv3, rv4, rv5, rv6, rv7);
            wb[wr][wc0 + 2] = blur7(rv2, rv3, rv4, rv5, rv6, rv7, rv8);
            wb[wr][wc0 + 3] = blur7(rv3, rv4, rv5, rv6, rv7, rv8, rv9);
        }

        lds_barrier();  // B: wb visible; raw reads drained

        // 4) H-blur pair: 8 wb reads -> 2 new ring values
        {
            float4 c0 = wb[2 * hp + 0][lw];
            float4 c1 = wb[2 * hp + 1][lw];
            float4 c2 = wb[2 * hp + 2][lw];
            float4 c3 = wb[2 * hp + 3][lw];
            float4 c4 = wb[2 * hp + 4][lw];
            float4 c5 = wb[2 * hp + 5][lw];
            float4 c6 = wb[2 * hp + 6][lw];
            float4 c7 = wb[2 * hp + 7][lw];
            float4 va = blur7(c0, c1, c2, c3, c4, c5, c6);
            float4 vb = blur7(c1, c2, c3, c4, c5, c6, c7);
            a0 = a1; a1 = a2; a2 = a3; a3 = a4; a4 = a5; a5 = a6; a6 = va;
            b0 = b1; b1 = b2; b2 = b3; b3 = b4; b4 = b5; b5 = b6; b6 = vb;
        }

        const int dout = din - 3;
        if (dout >= d0) {   // dout < d0+CHUNK by loop bound
            float4 oa = blur7(a0, a1, a2, a3, a4, a5, a6);
            float4 ob = blur7(b0, b1, b2, b3, b4, b5, b6);
            const size_t base = nbase + (size_t)dout * SLICE;
            out[base + (size_t)(h0 + 2 * hp + 0) * DIM + (w0 + lw)] = oa;
            out[base + (size_t)(h0 + 2 * hp + 1) * DIM + (w0 + lw)] = ob;
        }
        buf ^= 1;
    }
#undef PREFETCH
}

extern "C" void kernel_launch(void* const* d_in, const int* in_sizes, int n_in,
                              void* d_out, int out_size, void* d_ws, size_t ws_size,
                              hipStream_t stream) {
    const float4* in = (const float4*)d_in[0];
    float4* out = (float4*)d_out;
    gauss3d_fused<<<NBLK, 256, 0, stream>>>(in, out);
}

// Round 11
// 79.232 us; speedup vs baseline: 1.9956x; 1.0079x over previous
//
#include <hip/hip_runtime.h>

// Separable 3D Gaussian blur (sigma=1, truncate=3 -> 7 taps), SAME zero padding.
// (N=2, D=160, H=160, W=160, C=4) float32 == float4 over C.
// Round 11 = combine three individually-validated pieces:
//  - single-buffered raw (R8: hazards covered by the 2 lgkm barriers) ->
//    LDS 39.4 -> 25.6 KB -> 6 blocks/CU capacity
//  - CHUNK 10 (R8) -> 1600 blocks = 6.25/CU, matching the LDS cap
//  - bijective XCD-chunked swizzle (R10: FETCH 175->99 MB); 1600 = 8 x 200
// Rationale: R10 showed bytes are NOT the limiter (FETCH fell 43%, time flat);
// all pipes <35% busy -> latency/phase-serialization bound -> raise blocks/CU
// from 3.9 to ~6.25 to overlap the stage->W->H phase gaps.
// Unchanged: tile 16(H) x 32(W); 176 W-workers x (10 raw b128 reads -> 4 wb
// outputs); H-pairs with dual 7-deep D-rings; register prefetch 1 slice ahead;
// 2 lgkmcnt-only barriers/slice; launch_bounds(256,4) (VGPR cap 128; tighter
// caps spilled in R3/R7/R9 -> watch WRITE_SIZE ~136 MB as the spill canary).

#define THT 16             // tile height (H outputs)
#define TWT 32             // tile width  (W outputs)
#define CHUNK 10           // output D-slices per block
#define DIM 160
#define SLICE (DIM * DIM)  // float4 elements per (D) slice
#define RAWN (22 * 38)     // staged halo f4 per slice = 836
#define NBLK 1600          // 2 * 10 * 5 * 16

#define W0 0.004433048f
#define W1 0.054005582f
#define W2 0.242036229f
#define W3 0.399050300f

__device__ __forceinline__ float4 blur7(float4 a0, float4 a1, float4 a2, float4 a3,
                                        float4 a4, float4 a5, float4 a6) {
    float4 r;
    r.x = W0 * (a0.x + a6.x) + W1 * (a1.x + a5.x) + W2 * (a2.x + a4.x) + W3 * a3.x;
    r.y = W0 * (a0.y + a6.y) + W1 * (a1.y + a5.y) + W2 * (a2.y + a4.y) + W3 * a3.y;
    r.z = W0 * (a0.z + a6.z) + W1 * (a1.z + a5.z) + W2 * (a2.z + a4.z) + W3 * a3.z;
    r.w = W0 * (a0.w + a6.w) + W1 * (a1.w + a5.w) + W2 * (a2.w + a4.w) + W3 * a3.w;
    return r;
}

// Workgroup barrier with LDS visibility but NO vmcnt(0) drain -> prefetched
// global loads stay in flight across it.
__device__ __forceinline__ void lds_barrier() {
    asm volatile("s_waitcnt lgkmcnt(0)" ::: "memory");
    __builtin_amdgcn_s_barrier();
}

__global__ __launch_bounds__(256, 4)
void gauss3d_fused(const float4* __restrict__ in, float4* __restrict__ out) {
    // XCD-chunked bijective swizzle: 1600 = 8 * 200 exactly.
    int work = (blockIdx.x & 7) * (NBLK / 8) + (blockIdx.x >> 3);
    // decode: tw innermost, then th, chunk, n -> each XCD gets contiguous
    // spatial planes (all 50 tiles of ~4 D-chunks) -> halo re-reads L2-hit.
    const int tw    = work % (DIM / TWT);   work /= (DIM / TWT);   // 5
    const int th    = work % (DIM / THT);   work /= (DIM / THT);   // 10
    const int chunk = work % (DIM / CHUNK); work /= (DIM / CHUNK); // 16
    const int n     = work;                                        // 2

    const int h0 = th * THT;
    const int w0 = tw * TWT;
    const int d0 = chunk * CHUNK;

    __shared__ float4 raw[22][39];  // halo 22(H) x 38(W), odd col pad, single buf
    __shared__ float4 wb[22][33];   // W-blurred 22 x 32, odd col pad

    const int tid = threadIdx.x;
    const size_t nbase = (size_t)n * DIM * SLICE;
    const float4 z = make_float4(0.f, 0.f, 0.f, 0.f);

    // ---- stage constants: 836 halo f4 over 256 threads (<=4 slots) ----
    int  soff[4], rbidx[4];
    bool sok[4];
    #pragma unroll
    for (int s = 0; s < 4; ++s) {
        const int i = tid + 256 * s;
        const bool has = (i < RAWN);
        const int rr = has ? (i / 38) : 0, cc = has ? (i % 38) : 0;
        const int gh = h0 + rr - 3, gw = w0 + cc - 3;
        const bool ok = has && gh >= 0 && gh < DIM && gw >= 0 && gw < DIM;
        soff[s]  = ok ? (gh * DIM + gw) : 0;
        sok[s]   = ok;
        rbidx[s] = rr * 39 + cc;
    }
    const bool shas3 = (tid + 768 < RAWN);

    // ---- W-blur workers: 176 = 22 rows x 8 groups of 4 cols ----
    const bool isW = (tid < 176);
    const int wr  = tid >> 3;        // 0..21
    const int wc0 = (tid & 7) * 4;   // 0,4,...,28

    // ---- H-blur: 256 threads = 8 H-pairs x 32 cols ----
    const int hp = tid >> 5;         // 0..7 -> output rows 2hp, 2hp+1
    const int lw = tid & 31;         // 0..31

    float4 pf0, pf1, pf2, pf3;
    float4 a0 = z, a1 = z, a2 = z, a3 = z, a4 = z, a5 = z, a6 = z;  // ring row 2hp
    float4 b0 = z, b1 = z, b2 = z, b3 = z, b4 = z, b5 = z, b6 = z;  // ring row 2hp+1

#define PREFETCH(DSL)                                                        \
    do {                                                                     \
        const int _d = (DSL);                                                \
        const bool _inr = (_d >= 0) && (_d < DIM);                           \
        const float4* _s = in + nbase + (size_t)(_inr ? _d : 0) * SLICE;     \
        pf0 = (_inr && sok[0]) ? _s[soff[0]] : z;                            \
        pf1 = (_inr && sok[1]) ? _s[soff[1]] : z;                            \
        pf2 = (_inr && sok[2]) ? _s[soff[2]] : z;                            \
        pf3 = (_inr && sok[3]) ? _s[soff[3]] : z;                            \
    } while (0)

    PREFETCH(d0 - 3);

    for (int din = d0 - 3; din <= d0 + CHUNK + 2; ++din) {
        // 1) commit prefetched slice into raw (prev W-blur reads of raw
        //    drained at previous iteration's barrier B -> single buf safe)
        {
            float4* rb = &raw[0][0];
            rb[rbidx[0]] = pf0;
            rb[rbidx[1]] = pf1;
            rb[rbidx[2]] = pf2;
            if (shas3) rb[rbidx[3]] = pf3;
        }

        // 2) issue next slice's loads; in flight across both barriers
        PREFETCH(din + 1);

        lds_barrier();  // A: raw visible; prev H-blur reads of wb drained

        // 3) W-blur: 176 workers, 10 raw reads -> 4 wb outputs each
        if (isW) {
            float4 rv0 = raw[wr][wc0 + 0];
            float4 rv1 = raw[wr][wc0 + 1];
            float4 rv2 = raw[wr][wc0 + 2];
            float4 rv3 = raw[wr][wc0 + 3];
            float4 rv4 = raw[wr][wc0 + 4];
            float4 rv5 = raw[wr][wc0 + 5];
            float4 rv6 = raw[wr][wc0 + 6];
            float4 rv7 = raw[wr][wc0 + 7];
            float4 rv8 = raw[wr][wc0 + 8];
            float4 rv9 = raw[wr][wc0 + 9];
            wb[wr][wc0 + 0] = blur7(rv0, rv1, rv2, rv3, rv4, rv5, rv6);
            wb[wr][wc0 + 1] = blur7(rv1, rv2, rv3, rv4, rv5, rv6, rv7);
            wb[wr][wc0 + 2] = blur7(rv2, rv3, rv4, rv5, rv6, rv7, rv8);
            wb[wr][wc0 + 3] = blur7(rv3, rv4, rv5, rv6, rv7, rv8, rv9);
        }

        lds_barrier();  // B: wb visible; raw reads drained (next top rewrites)

        // 4) H-blur pair: 8 wb reads -> 2 new ring values
        {
            float4 c0 = wb[2 * hp + 0][lw];
            float4 c1 = wb[2 * hp + 1][lw];
            float4 c2 = wb[2 * hp + 2][lw];
            float4 c3 = wb[2 * hp + 3][lw];
            float4 c4 = wb[2 * hp + 4][lw];
            float4 c5 = wb[2 * hp + 5][lw];
            float4 c6 = wb[2 * hp + 6][lw];
            float4 c7 = wb[2 * hp + 7][lw];
            float4 va = blur7(c0, c1, c2, c3, c4, c5, c6);
            float4 vb = blur7(c1, c2, c3, c4, c5, c6, c7);
            a0 = a1; a1 = a2; a2 = a3; a3 = a4; a4 = a5; a5 = a6; a6 = va;
            b0 = b1; b1 = b2; b2 = b3; b3 = b4; b4 = b5; b5 = b6; b6 = vb;
        }

        const int dout = din - 3;
        if (dout >= d0) {   // dout < d0+CHUNK by loop bound
            float4 oa = blur7(a0, a1, a2, a3, a4, a5, a6);
            float4 ob = blur7(b0, b1, b2, b3, b4, b5, b6);
            const size_t base = nbase + (size_t)dout * SLICE;
            out[base + (size_t)(h0 + 2 * hp + 0) * DIM + (w0 + lw)] = oa;
            out[base + (size_t)(h0 + 2 * hp + 1) * DIM + (w0 + lw)] = ob;
        }
    }
#undef PREFETCH
}

extern "C" void kernel_launch(void* const* d_in, const int* in_sizes, int n_in,
                              void* d_out, int out_size, void* d_ws, size_t ws_size,
                              hipStream_t stream) {
    const float4* in = (const float4*)d_in[0];
    float4* out = (float4*)d_out;
    gauss3d_fused<<<NBLK, 256, 0, stream>>>(in, out);
}